// Round 1
// baseline (83.070 us; speedup 1.0000x reference)
//
#include <hip/hip_runtime.h>
#include <math.h>

// One block per image (B blocks, 256 threads). Thread p<196 simulates the
// 4-qubit circuit for patch p entirely in registers (16 complex amps).
// v3 algebraic cuts vs v2 (~36% fewer VALU ops/thread):
//  - last layer's U folded into the measurement: <Z_w> = <phi|M_w|phi>,
//    M = U^dag Z U = [[a,b],[b*,-a]] precomputed per wire in LDS
//  - boundary fusion V = RY(data) * U(l)  (8 FMAs) replaces separate RY apply (64 ops)
//  - peeled RY product state stays REAL through the CNOT ring and the first
//    fused gate on wire 0 (half-cost apply)
//  - gate precompute moved to idle wave-3 threads (tid>=196)

// Generic SU(2) apply: U = [[u0, u1],[-conj(u1), conj(u0)]]
#define APPLY_SU2(ST, U0R, U0I, U1R, U1I) do { \
  _Pragma("unroll") \
  for (int i = 0; i < 16; ++i) { \
    if (!(i & (ST))) { \
      float ar = sr[i], ai = si[i], br = sr[i + (ST)], bi = si[i + (ST)]; \
      sr[i]        =  (U0R) * ar - (U0I) * ai + (U1R) * br - (U1I) * bi; \
      si[i]        =  (U0R) * ai + (U0I) * ar + (U1R) * bi + (U1I) * br; \
      sr[i + (ST)] = -(U1R) * ar - (U1I) * ai + (U0R) * br + (U0I) * bi; \
      si[i + (ST)] = -(U1R) * ai + (U1I) * ar + (U0R) * bi - (U0I) * br; \
    } } } while (0)

#define APPLY_CNOT_C(SC, ST) do { \
  _Pragma("unroll") \
  for (int i = 0; i < 16; ++i) { \
    if ((i & (SC)) && !(i & (ST))) { \
      float tr = sr[i], ti = si[i]; \
      sr[i] = sr[i + (ST)]; si[i] = si[i + (ST)]; \
      sr[i + (ST)] = tr;    si[i + (ST)] = ti; \
    } } } while (0)

#define APPLY_CNOT_R(SC, ST) do { \
  _Pragma("unroll") \
  for (int i = 0; i < 16; ++i) { \
    if ((i & (SC)) && !(i & (ST))) { \
      float tr = rr[i]; rr[i] = rr[i + (ST)]; rr[i + (ST)] = tr; \
    } } } while (0)

#define CNOT_RING_C() do { \
  APPLY_CNOT_C(8, 4); APPLY_CNOT_C(4, 2); APPLY_CNOT_C(2, 1); APPLY_CNOT_C(1, 8); \
} while (0)

// V = RY(theta_w) * U(l,w); product of SU(2) stays SU(2):
//   V00 = c*u00 + s*conj(u01),  V01 = c*u01 - s*conj(u00)
#define FUSE_V(l, w) do { \
  const float* u_ = &uu[((l) * 4 + (w)) * 4]; \
  float fu0r = u_[0], fu0i = u_[1], fu1r = u_[2], fu1i = u_[3]; \
  float cw = dc[w], sw = ds[w]; \
  v0r = cw * fu0r + sw * fu1r; \
  v0i = cw * fu0i - sw * fu1i; \
  v1r = cw * fu1r - sw * fu0r; \
  v1i = cw * fu1i + sw * fu0i; \
} while (0)

// First fused gate (wire 0, ST=8) acting on the REAL state rr -> complex sr/si.
#define APPLY_SU2_REAL0() do { \
  _Pragma("unroll") \
  for (int i = 0; i < 8; ++i) { \
    float a_ = rr[i], b_ = rr[i + 8]; \
    sr[i]     = v0r * a_ + v1r * b_; \
    si[i]     = v0i * a_ + v1i * b_; \
    sr[i + 8] = v0r * b_ - v1r * a_; \
    si[i + 8] = v1i * a_ - v0i * b_; \
  } } while (0)

#define LAYER_V_FULL(l) do { \
  FUSE_V(l, 0); APPLY_SU2(8, v0r, v0i, v1r, v1i); \
  FUSE_V(l, 1); APPLY_SU2(4, v0r, v0i, v1r, v1i); \
  FUSE_V(l, 2); APPLY_SU2(2, v0r, v0i, v1r, v1i); \
  FUSE_V(l, 3); APPLY_SU2(1, v0r, v0i, v1r, v1i); \
  CNOT_RING_C(); \
} while (0)

template <int LC>   // LC = compile-time layer count; 0 = runtime loop
__global__ __launch_bounds__(256, 4) void quanv_fused_kernel(
    const float* __restrict__ x,    // (B,1,28,28)
    const float* __restrict__ qp,   // (L,4,3)
    const float* __restrict__ W,    // (10,784) row-major
    const float* __restrict__ bias, // (10,)
    float* __restrict__ out,        // (B,10)
    int Lrt)
{
  const int L = (LC > 0) ? LC : Lrt;
  const int n   = blockIdx.x;
  const int tid = threadIdx.x;
  const int p   = tid;            // patch index within image

  __shared__ float uu[8 * 16];    // layers 0..L-2: fused RZ*RY*RZ (u00r,u00i,u01r,u01i)
  __shared__ float mm[16];        // last layer folded into Z: (a, Br, Bi, pad) per wire

  // Gate precompute on the otherwise-idle wave-3 threads.
  if (tid >= 196 && tid < 196 + 4 * L) {
    const int k = tid - 196;
    const int l = k >> 2, w = k & 3;
    const float p0 = qp[l * 12 + w * 3 + 0];
    const float p1 = qp[l * 12 + w * 3 + 1];
    const float p2 = qp[l * 12 + w * 3 + 2];
    float c, s, ca, sa, cb, sb;
    __sincosf(0.5f * p1, &s, &c);
    __sincosf(0.5f * (p0 + p2), &sa, &ca);
    __sincosf(0.5f * (p0 - p2), &sb, &cb);
    const float u0r =  c * ca, u0i = -c * sa;   // u00
    const float u1r = -s * cb, u1i = -s * sb;   // u01
    if (l < L - 1) {
      float* u_ = &uu[(l * 4 + w) * 4];
      u_[0] = u0r; u_[1] = u0i; u_[2] = u1r; u_[3] = u1i;
    } else {
      // M = U^dag Z U = [[a, b],[conj(b), -a]], b = 2*conj(u00)*u01.
      // Store B = 2b so <Z> pair term is a*(pi-pj) + Br*xr - Bi*xi.
      float* m_ = &mm[w * 4];
      m_[0] = u0r * u0r + u0i * u0i - u1r * u1r - u1i * u1i;
      m_[1] = 4.f * (u0r * u1r + u0i * u1i);
      m_[2] = 4.f * (u0r * u1i - u0i * u1r);
    }
  }
  __syncthreads();

  float ez[4] = {0.f, 0.f, 0.f, 0.f};

  if (p < 196) {
    const int pr = p / 14, pcc = p % 14;
    const float2* xb = (const float2*)(x + (size_t)n * 784 + (2 * pr) * 28 + 2 * pcc);
    float2 top = xb[0], bot = xb[14];   // row stride 28 floats = 14 float2
    float dc[4], ds[4];
    __sincosf(0.5f * top.x, &ds[0], &dc[0]);
    __sincosf(0.5f * top.y, &ds[1], &dc[1]);
    __sincosf(0.5f * bot.x, &ds[2], &dc[2]);
    __sincosf(0.5f * bot.y, &ds[3], &dc[3]);

    // Data-RY on |0000>: real product state; CNOT ring is a free register permute.
    float rr[16];
    {
      float hi[4] = {dc[0]*dc[1], dc[0]*ds[1], ds[0]*dc[1], ds[0]*ds[1]};
      float lo[4] = {dc[2]*dc[3], dc[2]*ds[3], ds[2]*dc[3], ds[2]*ds[3]};
#pragma unroll
      for (int i = 0; i < 16; ++i) rr[i] = hi[i >> 2] * lo[i & 3];
    }
    APPLY_CNOT_R(8, 4); APPLY_CNOT_R(4, 2); APPLY_CNOT_R(2, 1); APPLY_CNOT_R(1, 8);

    float sr[16], si[16];
    float v0r, v0i, v1r, v1i;

    if (L >= 2) {
      // First fused layer: wire 0 consumes the real state at half cost.
      FUSE_V(0, 0); APPLY_SU2_REAL0();
      FUSE_V(0, 1); APPLY_SU2(4, v0r, v0i, v1r, v1i);
      FUSE_V(0, 2); APPLY_SU2(2, v0r, v0i, v1r, v1i);
      FUSE_V(0, 3); APPLY_SU2(1, v0r, v0i, v1r, v1i);
      CNOT_RING_C();
      if (LC > 0) {
#pragma unroll
        for (int l = 1; l < LC - 1; ++l) LAYER_V_FULL(l);
      } else {
        for (int l = 1; l < L - 1; ++l) LAYER_V_FULL(l);
      }
    } else {
#pragma unroll
      for (int i = 0; i < 16; ++i) { sr[i] = rr[i]; si[i] = 0.f; }
    }

    // Measurement with the folded last layer: per wire w (bit ST=8>>w),
    // <Z_w> = sum_pairs a*(p_i - p_j) + Br*xr - Bi*xi, x = conj(phi_i)*phi_j.
    float pp_[16];
#pragma unroll
    for (int i = 0; i < 16; ++i) pp_[i] = sr[i] * sr[i] + si[i] * si[i];
#pragma unroll
    for (int w = 0; w < 4; ++w) {
      const int ST = 8 >> w;
      const float aw = mm[w * 4 + 0], Br = mm[w * 4 + 1], Bi = mm[w * 4 + 2];
      float e = 0.f;
#pragma unroll
      for (int i = 0; i < 16; ++i) {
        if (!(i & ST)) {
          const int j = i + ST;
          float xr = sr[i] * sr[j] + si[i] * si[j];
          float xi = sr[i] * si[j] - si[i] * sr[j];
          e += aw * (pp_[i] - pp_[j]) + Br * xr - Bi * xi;
        }
      }
      ez[w] = e;
    }
  }

  // Per-patch partial logits: feats[4p+w] * W[c, 4p+w]; W row base is 16B aligned.
  float part[10];
#pragma unroll
  for (int c = 0; c < 10; ++c) part[c] = 0.f;
  if (p < 196) {
    const float4* Wv = (const float4*)W;
#pragma unroll
    for (int c = 0; c < 10; ++c) {
      float4 wc = Wv[c * 196 + p];
      part[c] = ez[0] * wc.x + ez[1] * wc.y + ez[2] * wc.z + ez[3] * wc.w;
    }
  }

  // Reduce across the block: wave64 shuffle, then combine 4 waves in LDS.
  const int lane = tid & 63;
  const int wave = tid >> 6;
  __shared__ float red[4][10];
#pragma unroll
  for (int c = 0; c < 10; ++c) {
    float v = part[c];
#pragma unroll
    for (int off = 32; off > 0; off >>= 1) v += __shfl_down(v, off, 64);
    if (lane == 0) red[wave][c] = v;
  }
  __syncthreads();

  if (tid == 0) {
    float logits[10];
    float m = -1e30f;
#pragma unroll
    for (int c = 0; c < 10; ++c) {
      logits[c] = red[0][c] + red[1][c] + red[2][c] + red[3][c] + bias[c];
      m = fmaxf(m, logits[c]);
    }
    float sum = 0.f;
#pragma unroll
    for (int c = 0; c < 10; ++c) sum += __expf(logits[c] - m);
    float lse = m + __logf(sum);
#pragma unroll
    for (int c = 0; c < 10; ++c) out[(size_t)n * 10 + c] = logits[c] - lse;
  }
}

extern "C" void kernel_launch(void* const* d_in, const int* in_sizes, int n_in,
                              void* d_out, int out_size, void* d_ws, size_t ws_size,
                              hipStream_t stream) {
  const float* x    = (const float*)d_in[0];
  const float* qp   = (const float*)d_in[1];
  const float* W    = (const float*)d_in[2];
  const float* bias = (const float*)d_in[3];
  float* out        = (float*)d_out;

  const int B = in_sizes[0] / 784;   // images
  const int L = in_sizes[1] / 12;    // layers

  switch (L) {
    case 1: quanv_fused_kernel<1><<<B, 256, 0, stream>>>(x, qp, W, bias, out, L); break;
    case 2: quanv_fused_kernel<2><<<B, 256, 0, stream>>>(x, qp, W, bias, out, L); break;
    case 3: quanv_fused_kernel<3><<<B, 256, 0, stream>>>(x, qp, W, bias, out, L); break;
    case 4: quanv_fused_kernel<4><<<B, 256, 0, stream>>>(x, qp, W, bias, out, L); break;
    default: quanv_fused_kernel<0><<<B, 256, 0, stream>>>(x, qp, W, bias, out, L); break;
  }
}